// Round 5
// baseline (10251.081 us; speedup 1.0000x reference)
//
#include <hip/hip_runtime.h>

// ---------------------------------------------------------------------------
// Seq2Seq LSTM + attention for MI355X (gfx950)
// B=256, T=512, I=64, H=512, HORIZON=30, NQ=3
// R12: split into 3 kernels (kenc / kproj / kdec) -> per-phase rocprof timing,
// kernel-boundary coherence replaces heavy barriers, kproj parallelized
// (2048 blocks, A-tile staged once, reused for 8 nt tiles).
// FAST flags: dual store (agent + sc0) with hybrid poll (sc0, every 16th
// agent) -- deadlock-proof. Encoder: x[s+1] prefetched INSIDE the barrier
// (after opening drain), closing barrier is raw s_barrier so the load stays
// in flight across it; x is oldest VMEM op so wait constants are unchanged.
// Carried from R11: 8 groups x 32 blocks XCD-local (runtime vote, SLOW
// fallback), both encoder layers per block, sc0 data traffic in FAST,
// conflict-free 3-sync K-split reduction, P2 register-hoisted attention.
// ---------------------------------------------------------------------------

typedef _Float16 half_t;
typedef __attribute__((ext_vector_type(8)))  _Float16 f16x8;
typedef __attribute__((ext_vector_type(16))) float    f32x16;

#define MFMA(a,b,c) __builtin_amdgcn_mfma_f32_32x32x16_f16((a),(b),(c),0,0,0)
#define CBAR()      asm volatile("" ::: "memory")

template<int N> __device__ __forceinline__ void waitvm() {
  asm volatile("s_waitcnt vmcnt(%0)" :: "n"(N) : "memory");
}

__device__ __forceinline__ float fsig(float x)  { return 1.0f / (1.0f + __expf(-x)); }
__device__ __forceinline__ float ftanh(float x) { return 1.0f - 2.0f / (1.0f + __expf(2.0f * x)); }

union FU { float f; unsigned u; };
union HU { _Float16 h; unsigned short u; };

// ---------------- coherent scalar ops: FAST = sc0 (XCD L2), SLOW = agent ----
template<bool FAST>
__device__ __forceinline__ float ldfa(const float* p) {
  if constexpr (FAST) {
    float v;
    asm volatile("global_load_dword %0, %1, off sc0\n\ts_waitcnt vmcnt(0)"
                 : "=v"(v) : "v"(p) : "memory");
    return v;
  } else {
    unsigned v = __hip_atomic_load((const unsigned*)p, __ATOMIC_RELAXED, __HIP_MEMORY_SCOPE_AGENT);
    FU c; c.u = v; return c.f;
  }
}
template<bool FAST>
__device__ __forceinline__ void stfa(float* p, float v) {
  FU c; c.f = v;
  if constexpr (FAST)
    asm volatile("global_store_dword %0, %1, off sc0" :: "v"(p), "v"(c.u) : "memory");
  else
    __hip_atomic_store((unsigned*)p, c.u, __ATOMIC_RELAXED, __HIP_MEMORY_SCOPE_AGENT);
}
template<bool FAST>
__device__ __forceinline__ void stha(half_t* p, float v) {
  HU c; c.h = (half_t)v;
  if constexpr (FAST)
    asm volatile("global_store_short %0, %1, off sc0" :: "v"(p), "v"((unsigned)c.u) : "memory");
  else
    __hip_atomic_store((unsigned short*)p, c.u, __ATOMIC_RELAXED, __HIP_MEMORY_SCOPE_AGENT);
}
template<bool FAST>
__device__ __forceinline__ void st64(float* p, float a, float b) {
  FU x, y; x.f = a; y.f = b;
  unsigned long long v = (unsigned long long)x.u | ((unsigned long long)y.u << 32);
  if constexpr (FAST)
    asm volatile("global_store_dwordx2 %0, %1, off sc0" :: "v"(p), "v"(v) : "memory");
  else
    __hip_atomic_store((unsigned long long*)p, v, __ATOMIC_RELAXED, __HIP_MEMORY_SCOPE_AGENT);
}
template<bool FAST>
__device__ __forceinline__ void ld64(const float* p, float& a, float& b) {
  unsigned long long v;
  if constexpr (FAST) {
    asm volatile("global_load_dwordx2 %0, %1, off sc0\n\ts_waitcnt vmcnt(0)"
                 : "=v"(v) : "v"(p) : "memory");
  } else {
    v = __hip_atomic_load((const unsigned long long*)p, __ATOMIC_RELAXED, __HIP_MEMORY_SCOPE_AGENT);
  }
  FU x, y; x.u = (unsigned)v; y.u = (unsigned)(v >> 32); a = x.f; b = y.f;
}

// ---------------- workspace layout (bytes, inside g_ws) ----------------
static constexpr size_t O_X16 = 0;                             // (T,B,128) f16 x zero-padded
static constexpr size_t O_WL0 = O_X16 + (size_t)512*256*128*2; // 32t x 5c packed  (2048x640)
static constexpr size_t O_WL1 = O_WL0 + (size_t)2048*640*2;    // 32t x 8c packed  (2048x1024)
static constexpr size_t O_WP1 = O_WL1 + (size_t)2048*1024*2;   // 73t x 4c packed  (4672x512)
static constexpr size_t O_WD0 = O_WP1 + (size_t)4672*512*2;    // 32t x 4c packed
static constexpr size_t O_WD1 = O_WD0 + (size_t)2048*512*2;    // 32t x 4c packed
static constexpr size_t O_BL0 = O_WD1 + (size_t)2048*512*2;    // 2048 f32 biases (gate-permuted)
static constexpr size_t O_BL1 = O_BL0 + 8192;
static constexpr size_t O_BD0 = O_BL1 + 8192;
static constexpr size_t O_BD1 = O_BD0 + 8192;
static constexpr size_t O_W0C = O_BD1 + 8192;                  // 2048 f32 dec_Wih0[:,0] permuted
static constexpr size_t O_H0B = O_W0C + 8192;                  // 2 x (256,512) f16 L0 h ping-pong
static constexpr size_t O_H1B = O_H0B + (size_t)2*256*512*2;   // 2 x (256,512) f16 L1 h ping-pong
static constexpr size_t O_HD1 = O_H1B + (size_t)2*256*512*2;   // (256,512) f16 decoder h1
static constexpr size_t O_H0D = O_HD1 + (size_t)256*512*2;     // (256,512) f16 decoder h0
static constexpr size_t O_CTX = O_H0D + (size_t)256*512*2;     // (256,512) f16 context
static constexpr size_t O_C0  = O_CTX + (size_t)256*512*2;     // (256,512) f32 (unused scratch)
static constexpr size_t O_C1  = O_C0  + (size_t)256*512*4;     // (256,512) f32
static constexpr size_t O_INP = O_C1  + (size_t)256*512*4;     // 256 f32
static constexpr size_t O_GAT = O_INP + 1024;                  // (256,4672) f32 gate partials
static constexpr size_t O_EO  = O_GAT + (size_t)256*4672*4;    // (B*T,H) f16 encoder outputs
static constexpr size_t O_EP  = O_EO  + (size_t)256*512*512*2; // (B*T,512) f16 enc_proj
static constexpr size_t WS_NEED = O_EP + (size_t)256*512*512*2;

__device__ __align__(4096) unsigned char g_ws[WS_NEED];
__device__ int g_bar[2048];    // vote-barrier lines
__device__ int g_flags[1024];  // 8 groups x 32 block flags (128B/group)
__device__ int g_xcc[256];     // per-block XCC id (+1)

#define WSH(o) ((half_t*)(g_ws + (o)))
#define WSCH(o) ((const half_t*)(g_ws + (o)))
#define WSF(o) ((float*)(g_ws + (o)))
#define WSCF(o) ((const float*)(g_ws + (o)))
#define BLINE(i) (g_bar + ((size_t)(i) << 5))

__device__ __forceinline__ int gperm(int n) { return (n & 3) * 512 + (n >> 2); }

// ---------------- flag publish / poll (deadlock-proof hybrid) ----------------
template<bool FAST>
__device__ __forceinline__ void flag_pub(int* p, int v) {
  __hip_atomic_store(p, v, __ATOMIC_RELAXED, __HIP_MEMORY_SCOPE_AGENT);  // L3 copy
  if constexpr (FAST)
    asm volatile("global_store_dword %0, %1, off sc0" :: "v"(p), "v"(v) : "memory");
}
template<bool FAST>
__device__ __forceinline__ void flag_poll(const int* fp, int step) {
  int it = 0;
  for (;;) {
    int v;
    ++it;
    if (FAST && (it & 15) != 0) {
      asm volatile("global_load_dword %0, %1, off sc0\n\ts_waitcnt vmcnt(0)"
                   : "=v"(v) : "v"(fp) : "memory");
    } else {
      v = __hip_atomic_load(fp, __ATOMIC_RELAXED, __HIP_MEMORY_SCOPE_AGENT);
    }
    if (__all(v >= step)) break;
    if (it > 6) __builtin_amdgcn_s_sleep(1);
  }
}
// full group barrier (decoder): drain + publish + poll + sync
template<bool FAST>
__device__ __forceinline__ void gbarf(int g, int r, int step) {
  __syncthreads();
  if (threadIdx.x < 64) {
    if (threadIdx.x == 0) flag_pub<FAST>(&g_flags[(g << 5) + r], step);
    flag_poll<FAST>(&g_flags[(g << 5) + (threadIdx.x & 31)], step);
  }
  __syncthreads();
}

// Grid barrier used once per kernel for the XCC vote.
__device__ __forceinline__ void gbar_acq8() {
  __syncthreads();
  if (threadIdx.x == 0) {
    const int g = blockIdx.x & 7;
    int* cnt = BLINE(g);
    int* mst = BLINE(8);
    int* gs  = BLINE(16 + g);
    int old = __hip_atomic_load(gs, __ATOMIC_RELAXED, __HIP_MEMORY_SCOPE_AGENT);
    int a = __hip_atomic_fetch_add(cnt, 1, __ATOMIC_ACQ_REL, __HIP_MEMORY_SCOPE_AGENT);
    if (a == 31) {
      __hip_atomic_store(cnt, 0, __ATOMIC_RELAXED, __HIP_MEMORY_SCOPE_AGENT);
      int m = __hip_atomic_fetch_add(mst, 1, __ATOMIC_ACQ_REL, __HIP_MEMORY_SCOPE_AGENT);
      if (m == 7) {
        __hip_atomic_store(mst, 0, __ATOMIC_RELAXED, __HIP_MEMORY_SCOPE_AGENT);
        for (int q = 0; q < 8; q++)
          __hip_atomic_fetch_add(BLINE(16 + q), 1, __ATOMIC_RELEASE, __HIP_MEMORY_SCOPE_AGENT);
      }
    }
    while (__hip_atomic_load(gs, __ATOMIC_RELAXED, __HIP_MEMORY_SCOPE_AGENT) == old)
      __builtin_amdgcn_s_sleep(2);
    (void)__hip_atomic_load(gs, __ATOMIC_ACQUIRE, __HIP_MEMORY_SCOPE_AGENT);
  }
  __syncthreads();
}

// vote: true iff my group's 32 blocks share one XCD and differ from neighbor
__device__ __forceinline__ bool xcd_vote(int g) {
  __shared__ int smode;
  int xcc = 0;
  asm volatile("s_getreg_b32 %0, hwreg(HW_REG_XCC_ID)" : "=s"(xcc));
  if (threadIdx.x == 0)
    __hip_atomic_store(&g_xcc[blockIdx.x], xcc + 1,
                       __ATOMIC_RELAXED, __HIP_MEMORY_SCOPE_AGENT);
  gbar_acq8();
  if (threadIdx.x < 64) {
    int p = __hip_atomic_load(&g_xcc[((threadIdx.x & 31) << 3) | g],
                              __ATOMIC_RELAXED, __HIP_MEMORY_SCOPE_AGENT);
    int q = __hip_atomic_load(&g_xcc[((threadIdx.x & 31) << 3) | (g ^ 1)],
                              __ATOMIC_RELAXED, __HIP_MEMORY_SCOPE_AGENT);
    int p0 = __builtin_amdgcn_readfirstlane(p);
    int ok = (__all(p == p0) && !__all(q == p0)) ? 1 : 0;
    if (threadIdx.x == 0) smode = ok;
  }
  __syncthreads();
  return smode != 0;
}

// ---------------- async global->LDS helper ----------------
template<int AX>
__device__ __forceinline__ void gld(const half_t* gp, char* lp) {
  __builtin_amdgcn_global_load_lds(
      (const __attribute__((address_space(1))) unsigned int*)gp,
      (__attribute__((address_space(3))) unsigned int*)lp, 16, 0, AX);
}

struct Seg { const half_t* p; int stride; int row0; };

__device__ __forceinline__ void stageA64(Seg s, int c, int lane, int wid, char* dst) {
  int kb = c * 128;
  const half_t* gp = s.p + (size_t)(s.row0 + (lane & 31)) * s.stride
                         + kb + (wid << 4) + ((lane >> 5) << 3);
  gld<0>(gp, dst);
  gld<0>(gp + (size_t)32 * s.stride, dst + 1024);
}

// ---------------- 32-row GEMM core (decoder phases) ----------------
template<int C, int NC>
__device__ __forceinline__ void kks32(char* wslr, f32x16 (&acc)[2][2],
                                      f16x8 (&b0)[4], f16x8 (&b1)[4]) {
  if constexpr (C < NC) {
    waitvm<3 * (NC - 1 - C) + 2>();
    f16x8 a = *(const f16x8*)(wslr + C * 8192);
    acc[0][0] = MFMA(a, b0[C], acc[0][0]);
    acc[0][1] = MFMA(a, b1[C], acc[0][1]);
    CBAR();
    kks32<C + 1, NC>(wslr, acc, b0, b1);
  }
}
template<int NC, int AX>
__device__ __forceinline__ void gemm_ks32(const half_t* aP, const half_t* Wt,
                                          int lane, int wid, char* asg, f32x16 (&acc)[2][2]) {
  char* wsl = asg + wid * 1024;
  const half_t* wb = Wt + (wid << 1) * 512 + lane * 8;
  f16x8 b0[4], b1[4];
  #pragma unroll
  for (int c = 0; c < NC; c++) {
    gld<AX>(aP + c * 128, wsl + c * 8192);
    CBAR();
    b0[c] = *(const f16x8*)(wb + (size_t)c * 8192);
    b1[c] = *(const f16x8*)(wb + (size_t)c * 8192 + 512);
    CBAR();
  }
  kks32<0, NC>(wsl + lane * 16, acc, b0, b1);
}

// ---------------- encoder K-bodies: 9 slots, weights in VGPRs --------
template<int C>
__device__ __forceinline__ void encL0(const char* wslr, const f16x8 (&B0)[5],
                                      const f16x8 (&B1)[5], f32x16 (&acc)[2][2]) {
  if constexpr (C < 5) {
    waitvm<8 - C>();
    f16x8 a = *(const f16x8*)(wslr + C * 8192);
    acc[0][0] = MFMA(a, B0[C], acc[0][0]);
    acc[0][1] = MFMA(a, B1[C], acc[0][1]);
    CBAR();
    encL0<C + 1>(wslr, B0, B1, acc);
  }
}
template<int C>
__device__ __forceinline__ void encL1(const char* wslr, const f16x8 (&B0)[8],
                                      const f16x8 (&B1)[8], f32x16 (&acc)[2][2]) {
  if constexpr (C < 8) {
    if constexpr (C >= 4) waitvm<7 - C>();
    f16x8 a = *(const f16x8*)(wslr + (C + 1) * 8192);
    acc[1][0] = MFMA(a, B0[C], acc[1][0]);
    acc[1][1] = MFMA(a, B1[C], acc[1][1]);
    CBAR();
    encL1<C + 1>(wslr, B0, B1, acc);
  }
}

// ---------------- K-split reduction: 3 syncs, conflict-free -----------------
__device__ __forceinline__ void acc_wr(float* dst, int lane, f32x16 acc[2][2]) {
  #pragma unroll
  for (int t = 0; t < 4; t++) {
    f32x16 a = acc[t >> 1][t & 1];
    #pragma unroll
    for (int r4 = 0; r4 < 4; r4++)
      *(float4*)(dst + ((t * 4 + r4) * 64 + lane) * 4) =
          make_float4(a[r4*4], a[r4*4+1], a[r4*4+2], a[r4*4+3]);
  }
}
__device__ __forceinline__ void acc_add(const float* src, int lane, f32x16 acc[2][2]) {
  #pragma unroll
  for (int t = 0; t < 4; t++) {
    #pragma unroll
    for (int r4 = 0; r4 < 4; r4++) {
      float4 v = *(const float4*)(src + ((t * 4 + r4) * 64 + lane) * 4);
      acc[t>>1][t&1][r4*4]   += v.x;
      acc[t>>1][t&1][r4*4+1] += v.y;
      acc[t>>1][t&1][r4*4+2] += v.z;
      acc[t>>1][t&1][r4*4+3] += v.w;
    }
  }
}
__device__ __forceinline__ void reduce8(f32x16 acc[2][2], float* red, int lane, int wid) {
  if (wid >= 4) acc_wr(red + (size_t)(wid - 4) * 4096, lane, acc);
  __syncthreads();
  if (wid < 4) acc_add(red + (size_t)wid * 4096, lane, acc);
  if (wid == 2 || wid == 3) acc_wr(red + (size_t)wid * 4096, lane, acc);
  __syncthreads();
  if (wid < 2) {
    acc_add(red + (size_t)(wid + 2) * 4096, lane, acc);
    float* zone = red + 8192 + (size_t)wid * 4096;
    #pragma unroll
    for (int ms = 0; ms < 2; ms++)
      #pragma unroll
      for (int ns = 0; ns < 2; ns++)
        #pragma unroll
        for (int rr = 0; rr < 16; rr++) {
          int row = ms * 32 + (rr & 3) + ((rr >> 2) << 3) + ((lane >> 5) << 2);
          zone[row * 64 + ns * 32 + (lane & 31)] = acc[ms][ns][rr];
        }
  }
  __syncthreads();
}
__device__ __forceinline__ float4 rsum4(const float* red, int row, int col) {
  float4 a = *(const float4*)&red[8192 + row * 64 + col];
  float4 b = *(const float4*)&red[12288 + row * 64 + col];
  return make_float4(a.x + b.x, a.y + b.y, a.z + b.z, a.w + b.w);
}

// ======================= ENCODER KERNEL =======================
template<bool FAST>
__device__ __noinline__ void enc_body(int g, int r, char* asg, float* red) {
  constexpr int AXH = FAST ? 1 : 17;
  constexpr size_t PP = (size_t)256 * 512;
  const half_t* x16 = WSCH(O_X16);
  half_t* h0bB = WSH(O_H0B);
  half_t* h1bB = WSH(O_H1B);
  half_t* eo   = WSH(O_EO);
  float* c1 = WSF(O_C1);

  const int tid = threadIdx.x;
  const int wid = tid >> 6;
  const int lane = tid & 63;
  const int m0 = g << 5;
  const f32x16 zv = {0,0,0,0,0,0,0,0,0,0,0,0,0,0,0,0};

  const int koff = (wid << 4) + ((lane >> 5) << 3);
  const size_t aofs = (size_t)(m0 + (lane & 31)) * 512 + koff;
  const size_t xofs = (size_t)(m0 + (lane & 31)) * 128 + koff;
  char* wsl = asg + wid * 1024;
  const char* wslr = wsl + lane * 16;

  const int n0 = r << 6;
  const half_t* wb0 = WSCH(O_WL0) + (size_t)r * (5 * 8192) + (wid << 1) * 512 + lane * 8;
  const half_t* wb1 = WSCH(O_WL1) + (size_t)r * (8 * 8192) + (wid << 1) * 512 + lane * 8;
  f16x8 B0L0[5], B1L0[5], B0L1[8], B1L1[8];
  #pragma unroll
  for (int c = 0; c < 5; c++) {
    B0L0[c] = *(const f16x8*)(wb0 + (size_t)c * 8192);
    B1L0[c] = *(const f16x8*)(wb0 + (size_t)c * 8192 + 512);
  }
  #pragma unroll
  for (int c = 0; c < 8; c++) {
    B0L1[c] = *(const f16x8*)(wb1 + (size_t)c * 8192);
    B1L1[c] = *(const f16x8*)(wb1 + (size_t)c * 8192 + 512);
  }
  const int eu = tid & 15, ebl = tid >> 4;
  const float4 breg0 = *(const float4*)&(WSCF(O_BL0))[n0 + eu * 4];
  const float4 breg1 = *(const float4*)&(WSCF(O_BL1))[n0 + eu * 4];
  const int bg = m0 + ebl, ug = (r << 4) + eu;
  float creg0 = 0.f, creg1 = 0.f;

  gld<0>(x16 + xofs, wsl);   // prefetch x[0] into slot 0 (oldest VMEM op)

  for (int s = 0; s <= 512; s++) {
    {  // stage h0 (slots 1..4), h1 (slots 5..8); x already in flight/resident
      const half_t* h0p = h0bB + (size_t)((s + 1) & 1) * PP + aofs;
      const half_t* h1p = h1bB + (size_t)(s & 1) * PP + aofs;
      #pragma unroll
      for (int c = 0; c < 4; c++) gld<AXH>(h0p + c * 128, wsl + (c + 1) * 8192);
      #pragma unroll
      for (int c = 0; c < 4; c++) gld<AXH>(h1p + c * 128, wsl + (c + 5) * 8192);
      CBAR();
    }
    f32x16 acc[2][2] = {{zv, zv}, {zv, zv}};
    encL0<0>(wslr, B0L0, B1L0, acc);
    encL1<0>(wslr, B0L1, B1L1, acc);
    reduce8(acc, red, lane, wid);
    if (s < 512) {                          // L0 epilogue
      float4 g4 = rsum4(red, ebl, eu * 4);
      float cn = fsig(g4.y + breg0.y) * creg0 + fsig(g4.x + breg0.x) * ftanh(g4.z + breg0.z);
      float hn = fsig(g4.w + breg0.w) * ftanh(cn);
      creg0 = cn;
      stha<FAST>(&h0bB[(size_t)(s & 1) * PP + (size_t)bg * 512 + ug], hn);
    }
    if (s > 0) {                            // L1 epilogue
      float4 g4 = rsum4(red, ebl + 32, eu * 4);
      float cn = fsig(g4.y + breg1.y) * creg1 + fsig(g4.x + breg1.x) * ftanh(g4.z + breg1.z);
      float hn = fsig(g4.w + breg1.w) * ftanh(cn);
      creg1 = cn;
      stha<FAST>(&h1bB[(size_t)((s + 1) & 1) * PP + (size_t)bg * 512 + ug], hn);
      eo[((size_t)bg * 512 + (s - 1)) * 512 + ug] = (half_t)hn;  // plain
    }
    // ---- inline barrier with cross-barrier x prefetch ----
    __syncthreads();                        // drains h publishes (vmcnt 0)
    {
      const int tc2 = (s < 511) ? (s + 1) : 511;
      gld<0>(x16 + (((size_t)tc2) << 15) + xofs, wsl);  // x[s+1], stays in flight
    }
    if (tid == 0) flag_pub<FAST>(&g_flags[(g << 5) + r], s + 1);
    if (tid < 64) flag_poll<FAST>(&g_flags[(g << 5) + (tid & 31)], s + 1);
    __builtin_amdgcn_s_barrier();           // raw: x prefetch survives
  }
  c1[(size_t)bg * 512 + ug] = creg1;        // plain; kernel boundary flushes
}

__global__ void __launch_bounds__(512, 2) kenc(int) {
  __shared__ __align__(16) char asg[73728];
  __shared__ float red[16384];
  const int g = blockIdx.x & 7;
  const int r = blockIdx.x >> 3;
  if (xcd_vote(g)) enc_body<true>(g, r, asg, red);
  else             enc_body<false>(g, r, asg, red);
}

// ======================= ENC_PROJ KERNEL (plain grid) =======================
__global__ void __launch_bounds__(512, 2) kproj(int) {
  __shared__ __align__(16) char asg[65536];   // 4 chunks x 8 waves x 2KB
  __shared__ float red[16384];
  const half_t* eo = WSCH(O_EO);
  const half_t* wP1 = WSCH(O_WP1);
  half_t* ep = WSH(O_EP);
  const int tid = threadIdx.x;
  const int wid = tid >> 6;
  const int lane = tid & 63;
  const f32x16 zv = {0,0,0,0,0,0,0,0,0,0,0,0,0,0,0,0};
  const int row0 = blockIdx.x * 64;           // 2048 row-tiles cover B*T rows

  // stage A (64 rows x 512 K) once; wave-private slots
  #pragma unroll
  for (int c = 0; c < 4; c++)
    stageA64(Seg{eo, 512, row0}, c, lane, wid, asg + (size_t)(c * 8 + wid) * 2048);
  waitvm<0>();
  CBAR();

  for (int nt = 0; nt < 8; nt++) {
    const half_t* wb = wP1 + (size_t)nt * (4 * 8192) + (wid << 1) * 512 + lane * 8;
    f32x16 acc[2][2] = {{zv, zv}, {zv, zv}};
    #pragma unroll
    for (int c = 0; c < 4; c++) {
      f16x8 b0 = *(const f16x8*)(wb + (size_t)c * 8192);
      f16x8 b1 = *(const f16x8*)(wb + (size_t)c * 8192 + 512);
      const char* ab = asg + (size_t)(c * 8 + wid) * 2048 + lane * 16;
      f16x8 a0 = *(const f16x8*)ab;
      f16x8 a1 = *(const f16x8*)(ab + 1024);
      acc[0][0] = MFMA(a0, b0, acc[0][0]);
      acc[0][1] = MFMA(a0, b1, acc[0][1]);
      acc[1][0] = MFMA(a1, b0, acc[1][0]);
      acc[1][1] = MFMA(a1, b1, acc[1][1]);
    }
    reduce8(acc, red, lane, wid);
    {
      int row = tid >> 3, col = (tid & 7) * 8;
      float4 a0 = rsum4(red, row, col);
      float4 a1 = rsum4(red, row, col + 4);
      f16x8 h8;
      h8[0] = (half_t)a0.x; h8[1] = (half_t)a0.y; h8[2] = (half_t)a0.z; h8[3] = (half_t)a0.w;
      h8[4] = (half_t)a1.x; h8[5] = (half_t)a1.y; h8[6] = (half_t)a1.z; h8[7] = (half_t)a1.w;
      *(f16x8*)&ep[(size_t)(row0 + row) * 512 + nt * 64 + col] = h8;
    }
    __syncthreads();
  }
}

// ======================= DECODER KERNEL =======================
template<bool FAST>
__device__ __noinline__ void dec_body(int g, int r, const float* attn_v,
                                      const float* out_b, float* out,
                                      char* asg, float* red) {
  constexpr int AXH = FAST ? 1 : 17;
  constexpr size_t PP = (size_t)256 * 512;
  const half_t* wP1 = WSCH(O_WP1);
  const half_t* wD0 = WSCH(O_WD0);
  const half_t* wD1 = WSCH(O_WD1);
  half_t* h1bB = WSH(O_H1B);
  half_t* hd1  = WSH(O_HD1);
  half_t* h0d  = WSH(O_H0D);
  half_t* ctx  = WSH(O_CTX);
  const half_t* eo = WSCH(O_EO);
  const half_t* ep = WSCH(O_EP);
  float* c1 = WSF(O_C1);
  float* inp = WSF(O_INP);
  float* gates = WSF(O_GAT);

  const int tid = threadIdx.x;
  const int wid = tid >> 6;
  const int lane = tid & 63;
  const int m0 = g << 5;
  const f32x16 zv = {0,0,0,0,0,0,0,0,0,0,0,0,0,0,0,0};
  int bstep = 1024;   // above kenc's 513 step range (flags not re-zeroed)

  const int koff = (wid << 4) + ((lane >> 5) << 3);
  const size_t aofs = (size_t)(m0 + (lane & 31)) * 512 + koff;

  for (int d = 0; d <= 30; d++) {
    const half_t* hs = (d == 0) ? (h1bB + PP) : hd1;

    // ---- P1: h1 @ [attn_W | dWhh0 | dWhh1 | out_W], 73 tiles / 32 blocks ----
    for (int jj = r; jj < 73; jj += 32) {
      if (d == 30 && jj != 72) continue;
      f32x16 acc[2][2] = {{zv, zv}, {zv, zv}};
      gemm_ks32<4, AXH>(hs + aofs, wP1 + (size_t)jj * (4 * 8192), lane, wid, asg, acc);
      reduce8(acc, red, lane, wid);
      if (jj < 72) {
        int row = tid >> 4, col = (tid & 15) * 4;
        float4 v4 = rsum4(red, row, col);
        float* dst = &gates[(size_t)(m0 + row) * 4672 + jj * 64 + col];
        st64<FAST>(dst, v4.x, v4.y);
        st64<FAST>(dst + 2, v4.z, v4.w);
      } else if (d > 0) {
        if (tid < 32) {
          int bg = m0 + tid;
          float v0 = red[8192 + tid * 64 + 0] + red[12288 + tid * 64 + 0] + out_b[0];
          float v1 = red[8192 + tid * 64 + 1] + red[12288 + tid * 64 + 1] + out_b[1];
          float v2 = red[8192 + tid * 64 + 2] + red[12288 + tid * 64 + 2] + out_b[2];
          out[(size_t)bg * 90 + (d - 1) * 3 + 0] = v0;
          out[(size_t)bg * 90 + (d - 1) * 3 + 1] = v1;
          out[(size_t)bg * 90 + (d - 1) * 3 + 2] = v2;
          stfa<FAST>(&inp[bg], v1);
        }
      }
      __syncthreads();
    }
    gbarf<FAST>(g, r, ++bstep);
    if (d == 30) break;

    // ---- P2: attention for batch row b = m0 + r ----
    {
      const int b = m0 + r;
      float* dpb = red;
      float* vb  = red + 512;
      float* eb  = red + 1024;
      float* ab2 = red + 2048;
      float* sc  = red + 2560;
      float* pm  = red + 4096;
      dpb[tid] = ldfa<FAST>(&gates[(size_t)b * 4672 + tid]);
      vb[tid]  = attn_v[tid];
      __syncthreads();
      float va[8], da[8];
      {
        float4 t0 = *(const float4*)&vb[lane * 8];
        float4 t1 = *(const float4*)&vb[lane * 8 + 4];
        float4 t2 = *(const float4*)&dpb[lane * 8];
        float4 t3 = *(const float4*)&dpb[lane * 8 + 4];
        va[0]=t0.x; va[1]=t0.y; va[2]=t0.z; va[3]=t0.w;
        va[4]=t1.x; va[5]=t1.y; va[6]=t1.z; va[7]=t1.w;
        da[0]=t2.x; da[1]=t2.y; da[2]=t2.z; da[3]=t2.w;
        da[4]=t3.x; da[5]=t3.y; da[6]=t3.z; da[7]=t3.w;
      }
      const half_t* eprow = ep + ((size_t)b << 18) + (size_t)(wid * 64) * 512 + lane * 8;
      for (int tt = 0; tt < 64; tt++) {
        f16x8 e8 = *(const f16x8*)(eprow + (size_t)tt * 512);
        float sum = 0.f;
        #pragma unroll
        for (int jq = 0; jq < 8; jq++)
          sum += va[jq] * ftanh((float)e8[jq] + da[jq]);
        #pragma unroll
        for (int off = 32; off > 0; off >>= 1) sum += __shfl_down(sum, off, 64);
        if (lane == 0) eb[wid * 64 + tt] = sum;
      }
      __syncthreads();
      float e0 = eb[tid];
      float mx = e0;
      #pragma unroll
      for (int off = 32; off > 0; off >>= 1) mx = fmaxf(mx, __shfl_xor(mx, off, 64));
      if (lane == 0) sc[wid] = mx;
      __syncthreads();
      mx = sc[0];
      #pragma unroll
      for (int q = 1; q < 8; q++) mx = fmaxf(mx, sc[q]);
      float x0 = __expf(e0 - mx);
      float ssum = x0;
      #pragma unroll
      for (int off = 32; off > 0; off >>= 1) ssum += __shfl_xor(ssum, off, 64);
      __syncthreads();
      if (lane == 0) sc[8 + wid] = ssum;
      __syncthreads();
      float tot = sc[8];
      #pragma unroll
      for (int q = 1; q < 8; q++) tot += sc[8 + q];
      float inv = 1.f / tot;
      ab2[tid] = x0 * inv;
      __syncthreads();
      float pacc[8] = {0,0,0,0,0,0,0,0};
      const half_t* eow = eo + ((size_t)b << 18) + (size_t)(wid * 64) * 512 + lane * 8;
      for (int tt = 0; tt < 64; tt++) {
        f16x8 h8 = *(const f16x8*)(eow + (size_t)tt * 512);
        float at = ab2[wid * 64 + tt];
        #pragma unroll
        for (int jq = 0; jq < 8; jq++) pacc[jq] += at * (float)h8[jq];
      }
      #pragma unroll
      for (int jq = 0; jq < 8; jq++) pm[wid * 512 + lane * 8 + jq] = pacc[jq];
      __syncthreads();
      float sctx = 0.f;
      #pragma unroll
      for (int w = 0; w < 8; w++) sctx += pm[w * 512 + tid];
      stha<FAST>(&ctx[((size_t)b << 9) + tid], sctx);
    }
    gbarf<FAST>(g, r, ++bstep);

    // ---- P3: gates0 = ctx @ dWih0[:,1:] + inp*w0col + partial -> h0d ----
    {
      f32x16 acc[2][2] = {{zv, zv}, {zv, zv}};
      gemm_ks32<4, AXH>(ctx + aofs, wD0 + (size_t)r * (4 * 8192), lane, wid, asg, acc);
      reduce8(acc, red, lane, wid);
      const float* bD0 = WSCF(O_BD0);
      const float* w0c = WSCF(O_W0C);
      int u = tid & 15, bl = tid >> 4;
      int bg = m0 + bl, ug = (r << 4) + u, nl = (r << 6) + u * 4;
      float4 g4 = rsum4(red, bl, u * 4);
      float p0, p1, p2, p3;
      ld64<FAST>(&gates[(size_t)bg * 4672 + 512 + nl], p0, p1);
      ld64<FAST>(&gates[(size_t)bg * 4672 + 512 + nl + 2], p2, p3);
      float4 b4 = *(const float4*)&bD0[nl];
      float4 w4 = *(const float4*)&w0c[nl];
      float iv = ldfa<FAST>(&inp[bg]);
      float gi = g4.x + p0 + b4.x + iv * w4.x;
      float gf = g4.y + p1 + b4.y + iv * w4.y;
      float gz = g4.z + p2 + b4.z + iv * w4.z;
      float go = g4.w + p3 + b4.w + iv * w4.w;
      float cold = c1[(size_t)bg * 512 + ug];
      float cn = fsig(gf) * cold + fsig(gi) * ftanh(gz);
      stha<FAST>(&h0d[(size_t)bg * 512 + ug], fsig(go) * ftanh(cn));
    }
    gbarf<FAST>(g, r, ++bstep);

    // ---- P4: gates1 = h0d @ dWih1 + partial + bias -> c1, hd1 ----
    {
      f32x16 acc[2][2] = {{zv, zv}, {zv, zv}};
      gemm_ks32<4, AXH>(h0d + aofs, wD1 + (size_t)r * (4 * 8192), lane, wid, asg, acc);
      reduce8(acc, red, lane, wid);
      const float* bD1 = WSCF(O_BD1);
      int u = tid & 15, bl = tid >> 4;
      int bg = m0 + bl, ug = (r << 4) + u, nl = (r << 6) + u * 4;
      float4 g4 = rsum4(red, bl, u * 4);
      float p0, p1, p2, p3;
      ld64<FAST>(&gates[(size_t)bg * 4672 + 2560 + nl], p0, p1);
      ld64<FAST>(&gates[(size_t)bg * 4672 + 2560 + nl + 2], p2, p3);
      float4 b4 = *(const float4*)&bD1[nl];
      float gi = g4.x + p0 + b4.x;
      float gf = g4.y + p1 + b4.y;
      float gz = g4.z + p2 + b4.z;
      float go = g4.w + p3 + b4.w;
      float cold = c1[(size_t)bg * 512 + ug];
      float cn = fsig(gf) * cold + fsig(gi) * ftanh(gz);
      float hn = fsig(go) * ftanh(cn);
      c1[(size_t)bg * 512 + ug] = cn;
      stha<FAST>(&hd1[(size_t)bg * 512 + ug], hn);
    }
    gbarf<FAST>(g, r, ++bstep);
  }
}

__global__ void __launch_bounds__(512, 2) kdec(const float* __restrict__ attn_v,
                                               const float* __restrict__ out_b,
                                               float* __restrict__ out) {
  __shared__ __align__(16) char asg[32768];
  __shared__ float red[16384];
  const int g = blockIdx.x & 7;
  const int r = blockIdx.x >> 3;
  if (xcd_vote(g)) dec_body<true>(g, r, attn_v, out_b, out, asg, red);
  else             dec_body<false>(g, r, attn_v, out_b, out, asg, red);
}

// ---------------- prep kernels ----------------
__global__ void kpackB(size_t dstOff, int id, int Ntiles, int NC,
                       const float* s0, const float* s1,
                       const float* s2, const float* s3) {
  half_t* dst = (half_t*)(g_ws + dstOff);
  size_t total = (size_t)Ntiles * NC * 8192;
  size_t i = (size_t)blockIdx.x * 256 + threadIdx.x;
  size_t stride = (size_t)gridDim.x * 256;
  for (size_t e = i; e < total; e += stride) {
    int j = e & 7;
    int l = (e >> 3) & 63;
    int bh = (e >> 9) & 1;
    int w = (e >> 10) & 7;
    int tc = (int)(e >> 13);
    int c = tc % NC;
    int tile = tc / NC;
    int n = tile * 64 + bh * 32 + (l & 31);
    int k = c * 128 + w * 16 + ((l >> 5) << 3) + j;
    float v = 0.f;
    if (id == 0) {          // wL0: [Wih0(64) | pad(64) | Whh0(512)]
      int pn = gperm(n);
      if (k < 64) v = s0[(size_t)pn * 64 + k];
      else if (k >= 128) v = s1[(size_t)pn * 512 + (k - 128)];
    } else if (id == 1) {   // wL1: [Wih1(512) | Whh1(512)]
      int pn = gperm(n);
      v = (k < 512) ? s0[(size_t)pn * 512 + k] : s1[(size_t)pn * 512 + (k - 512)];
    } else if (id == 2) {   // wP1: [attnW | dWhh0 | dWhh1 | outW | pad]
      if (n < 512) v = s0[((size_t)n << 9) + k];
      else if (n < 2560) v = s1[((size_t)gperm(n - 512) << 9) + k];
      else if (n < 4608) v = s2[((size_t)gperm(n - 2560) << 9) + k];
      else if (n < 4611) v = s3[((size_t)(n - 4608) << 9) + k];
    } else if (id == 3) {   // wD0: dec_Wih0[:,1:]
      v = s0[(size_t)gperm(n) * 513 + 1 + k];
    } else {                // wD1
      v = s0[((size_t)gperm(n) << 9) + k];
    }
    dst[e] = (half_t)v;
  }
}

__global__ void kmisc(const float* ebih0, const float* ebhh0, const float* ebih1, const float* ebhh1,
                      const float* dbih0, const float* dbhh0, const float* dbih1, const float* dbhh1,
                      const float* dWih0, const float* x) {
  float* bL0 = WSF(O_BL0);
  float* bL1 = WSF(O_BL1);
  float* bD0 = WSF(O_BD0);
  float* bD1 = WSF(O_BD1);
  float* w0c = WSF(O_W0C);
  half_t* h0b = WSH(O_H0B);
  half_t* h1b = WSH(O_H1B);
  float* c1 = WSF(O_C1);
  float* inp = WSF(O_INP);
  int i = blockIdx.x * 256 + threadIdx.x, stride = gridDim.x * 256;
  for (int idx = i; idx < 262144; idx += stride) {
    if (idx < 2048) {
      int pn = gperm(idx);
      bL0[idx] = ebih0[pn] + ebhh0[pn];
      bL1[idx] = ebih1[pn] + ebhh1[pn];
      bD0[idx] = dbih0[pn] + dbhh0[pn];
      bD1[idx] = dbih1[pn] + dbhh1[pn];
      w0c[idx] = dWih0[(size_t)pn * 513];
      g_bar[idx] = 0;
    }
    if (idx < 1024) g_flags[idx] = 0;
    if (idx < 256) { inp[idx] = x[((size_t)idx * 512 + 511) * 64]; g_xcc[idx] = 0; }
    h0b[idx] = (half_t)0.f;
    h1b[idx] = (half_t)0.f;
    if (idx < 131072) c1[idx] = 0.f;
  }
}

__global__ void kx16(const float* x) {
  half_t* dst = WSH(O_X16);   // (t, b, 128) zero-padded cols 64..127
  size_t i = (size_t)blockIdx.x * 256 + threadIdx.x;
  size_t stride = (size_t)gridDim.x * 256;
  for (size_t e = i; e < (size_t)512 * 256 * 128; e += stride) {
    int t = (int)(e >> 15);
    int b = (int)((e >> 7) & 255);
    int ii = (int)(e & 127);
    dst[e] = (ii < 64) ? (half_t)x[((size_t)b * 512 + t) * 64 + ii] : (half_t)0.f;
  }
}

// ---------------- launch ----------------
extern "C" void kernel_launch(void* const* d_in, const int* in_sizes, int n_in,
                              void* d_out, int out_size, void* d_ws, size_t ws_size,
                              hipStream_t stream) {
  const float* x     = (const float*)d_in[0];
  const float* eWih0 = (const float*)d_in[1];
  const float* eWhh0 = (const float*)d_in[2];
  const float* ebih0 = (const float*)d_in[3];
  const float* ebhh0 = (const float*)d_in[4];
  const float* eWih1 = (const float*)d_in[5];
  const float* eWhh1 = (const float*)d_in[6];
  const float* ebih1 = (const float*)d_in[7];
  const float* ebhh1 = (const float*)d_in[8];
  const float* dWih0 = (const float*)d_in[9];
  const float* dWhh0 = (const float*)d_in[10];
  const float* dbih0 = (const float*)d_in[11];
  const float* dbhh0 = (const float*)d_in[12];
  const float* dWih1 = (const float*)d_in[13];
  const float* dWhh1 = (const float*)d_in[14];
  const float* dbih1 = (const float*)d_in[15];
  const float* dbhh1 = (const float*)d_in[16];
  const float* attnW = (const float*)d_in[17];
  const float* attnv = (const float*)d_in[18];
  const float* outW  = (const float*)d_in[19];
  const float* outb  = (const float*)d_in[20];
  (void)in_sizes; (void)n_in; (void)out_size; (void)d_ws; (void)ws_size;

  kpackB<<<1024, 256, 0, stream>>>(O_WL0, 0, 32, 5, eWih0, eWhh0, nullptr, nullptr);
  kpackB<<<1024, 256, 0, stream>>>(O_WL1, 1, 32, 8, eWih1, eWhh1, nullptr, nullptr);
  kpackB<<<1024, 256, 0, stream>>>(O_WP1, 2, 73, 4, attnW, dWhh0, dWhh1, outW);
  kpackB<<<1024, 256, 0, stream>>>(O_WD0, 3, 32, 4, dWih0, nullptr, nullptr, nullptr);
  kpackB<<<1024, 256, 0, stream>>>(O_WD1, 4, 32, 4, dWih1, nullptr, nullptr, nullptr);
  kmisc<<<1024, 256, 0, stream>>>(ebih0, ebhh0, ebih1, ebhh1,
                                  dbih0, dbhh0, dbih1, dbhh1, dWih0, x);
  kx16<<<2048, 256, 0, stream>>>(x);

  int zero = 0;
  void* eargs[] = {(void*)&zero};
  hipError_t e1 = hipLaunchCooperativeKernel((void*)kenc, dim3(256), dim3(512),
                                             eargs, 0, stream);
  if (e1 != hipSuccess) kenc<<<dim3(256), dim3(512), 0, stream>>>(0);

  kproj<<<dim3(2048), dim3(512), 0, stream>>>(0);

  float* outp = (float*)d_out;
  void* dargs[] = {(void*)&attnv, (void*)&outb, (void*)&outp};
  hipError_t e2 = hipLaunchCooperativeKernel((void*)kdec, dim3(256), dim3(512),
                                             dargs, 0, stream);
  if (e2 != hipSuccess) kdec<<<dim3(256), dim3(512), 0, stream>>>(attnv, outb, outp);
}